// Round 4
// baseline (577.837 us; speedup 1.0000x reference)
//
#include <hip/hip_runtime.h>
#include <math.h>

// ---------------- problem constants ----------------
#define NB      8732          // number of default boxes
#define NCLS    81            // classes incl. background
#define NFG     80            // foreground classes
#define TOPK    200           // per-class NMS candidates
#define MAXOUT  20            // final detections
#define SCORE_MIN_F 0.05f
#define NMS_IOU_F   0.5f
#define CONF_TH_F   0.2f
#define OHW     300
#define IHW     4096
#define X_ELEMS (3*OHW*OHW)   // 270000
#define B_OFF   270000
#define L_OFF   270080
#define S_OFF   270100
#define V_OFF   270120
#define NFLAT   (NFG * TOPK)  // 16000

typedef unsigned long long ull;

__device__ __constant__ int COCO[81] = {
  1,2,3,4,5,6,7,8,9,10,11,13,14,15,16,17,18,19,20,21,22,23,24,25,27,28,31,32,
  33,34,35,36,37,38,39,40,41,42,43,44,46,47,48,49,50,51,52,53,54,55,56,57,58,
  59,60,61,62,63,64,65,67,70,72,73,74,75,76,77,78,79,80,81,82,84,85,86,87,88,
  89,90,91};

// ---------------- kernel 1: normalize + bilinear resize (align_corners) ----
// One block per (channel, output-row): stage the two source rows into LDS
// with coalesced float4 loads, then compute 300 outputs from LDS.
__global__ __launch_bounds__(256) void resize_kernel(const float* __restrict__ img,
                                                     float* __restrict__ out)
{
    const int b   = blockIdx.x;       // 0..899
    const int tid = threadIdx.x;
    const int ch  = b / OHW;
    const int oy  = b % OHW;

    const float r = (float)(4095.0 / 299.0);   // f32, matches jnp f32 promote
    float sy = (float)oy * r;
    int y0 = (int)floorf(sy);
    y0 = min(max(y0, 0), IHW - 2);
    float wy = sy - (float)y0;

    __shared__ __align__(16) float r0s[IHW];
    __shared__ __align__(16) float r1s[IHW];

    const float* p0 = img + (size_t)ch * IHW * IHW + (size_t)y0 * IHW;
    const float* p1 = p0 + IHW;
    #pragma unroll 4
    for (int i = tid; i < IHW / 4; i += 256) {
        float4 a = ((const float4*)p0)[i];
        float4 c = ((const float4*)p1)[i];
        a.x = (a.x * 255.0f - 128.0f) / 128.0f;
        a.y = (a.y * 255.0f - 128.0f) / 128.0f;
        a.z = (a.z * 255.0f - 128.0f) / 128.0f;
        a.w = (a.w * 255.0f - 128.0f) / 128.0f;
        c.x = (c.x * 255.0f - 128.0f) / 128.0f;
        c.y = (c.y * 255.0f - 128.0f) / 128.0f;
        c.z = (c.z * 255.0f - 128.0f) / 128.0f;
        c.w = (c.w * 255.0f - 128.0f) / 128.0f;
        ((float4*)r0s)[i] = a;
        ((float4*)r1s)[i] = c;
    }
    __syncthreads();

    float* orow = out + (size_t)ch * OHW * OHW + (size_t)oy * OHW;
    for (int ox = tid; ox < OHW; ox += 256) {
        float sx = (float)ox * r;
        int x0 = (int)floorf(sx);
        x0 = min(max(x0, 0), IHW - 2);
        float wx = sx - (float)x0;
        float left  = r0s[x0]     * (1.0f - wy) + r1s[x0]     * wy;
        float right = r0s[x0 + 1] * (1.0f - wy) + r1s[x0 + 1] * wy;
        orow[ox] = left * (1.0f - wx) + right * wx;
    }
}

// ---------------- kernel 2: decode boxes + softmax scores -----------------
__global__ __launch_bounds__(256) void decode_kernel(const float* __restrict__ ploc,
                                                     const float* __restrict__ plabel,
                                                     const float* __restrict__ dboxes,
                                                     float* __restrict__ ltrb,
                                                     float* __restrict__ scores_t)
{
    int i = blockIdx.x * 256 + threadIdx.x;
    if (i >= NB) return;

    float l0 = ploc[0 * NB + i];
    float l1 = ploc[1 * NB + i];
    float l2 = ploc[2 * NB + i];
    float l3 = ploc[3 * NB + i];
    float4 db = ((const float4*)dboxes)[i];   // x,y,w,h
    float x = (l0 * 0.1f) * db.z + db.x;
    float y = (l1 * 0.1f) * db.w + db.y;
    float w = expf(l2 * 0.2f) * db.z;
    float h = expf(l3 * 0.2f) * db.w;
    float4 bb;
    bb.x = x - 0.5f * w;
    bb.y = y - 0.5f * h;
    bb.z = x + 0.5f * w;
    bb.w = y + 0.5f * h;
    ((float4*)ltrb)[i] = bb;

    // softmax over 81 classes (column i of plabel [81, NB])
    float mx = -1e30f;
    #pragma unroll 4
    for (int k = 0; k < NCLS; k++) mx = fmaxf(mx, plabel[k * NB + i]);
    float s = 0.0f;
    #pragma unroll 4
    for (int k = 0; k < NCLS; k++) s += expf(plabel[k * NB + i] - mx);
    #pragma unroll 4
    for (int c = 0; c < NFG; c++) {
        float e = expf(plabel[(c + 1) * NB + i] - mx);
        scores_t[c * NB + i] = e / s;
    }
}

// ---------------- helpers -------------------------------------------------
__device__ __forceinline__ void bmax3(float& av, int& ai, int& ap,
                                      float v, int i, int p)
{
    if (v > av || (v == av && i < ai)) { av = v; ai = i; ap = p; }
}

__device__ __forceinline__ void block_best(float bv, int bi, int bp,
                                           float* swv, int* swi, int* swp,
                                           volatile float* outv, volatile int* outi,
                                           volatile int* outp, int tid)
{
    for (int off = 32; off; off >>= 1) {
        float v2 = __shfl_down(bv, off, 64);
        int   i2 = __shfl_down(bi, off, 64);
        int   p2 = __shfl_down(bp, off, 64);
        bmax3(bv, bi, bp, v2, i2, p2);
    }
    int wid = tid >> 6;
    if ((tid & 63) == 0) { swv[wid] = bv; swi[wid] = bi; swp[wid] = bp; }
    __syncthreads();
    if (tid == 0) {
        float gv = swv[0]; int gi = swi[0]; int gp = swp[0];
        for (int w = 1; w < 4; w++) bmax3(gv, gi, gp, swv[w], swi[w], swp[w]);
        *outv = gv; *outi = gi; *outp = gp;
    }
    __syncthreads();
}

// Pair-indexed bitonic sort, descending, u64 keys in LDS. 256 threads.
// Each inner step: N/2 independent compare-exchanges, ILP across the p-loop.
__device__ __forceinline__ void bitonic_desc(ull* key, int N, int tid)
{
    for (int k2 = 2; k2 <= N; k2 <<= 1) {
        for (int j = k2 >> 1; j > 0; j >>= 1) {
            __syncthreads();
            for (int p = tid; p < (N >> 1); p += 256) {
                int i = ((p & ~(j - 1)) << 1) | (p & (j - 1));
                int l = i | j;
                ull a = key[i], b = key[l];
                bool desc = ((i & k2) == 0);
                if (desc ? (a < b) : (a > b)) { key[i] = b; key[l] = a; }
            }
        }
    }
    __syncthreads();
}

// ---------------- kernel 3: per-class top-200 + greedy NMS ----------------
#define SORT_CAP 4096

__global__ __launch_bounds__(256) void nms_kernel(const float* __restrict__ scores_t,
                                                  const float* __restrict__ ltrb,
                                                  float* __restrict__ cls_scores,
                                                  int* __restrict__ cls_bidx)
{
    const int c   = blockIdx.x;
    const int tid = threadIdx.x;

    __shared__ __align__(16) ull skey[SORT_CAP];           // 32 KB
    __shared__ int   scount;
    __shared__ float cval[TOPK];
    __shared__ int   cbid[TOPK];
    __shared__ float4 cbox[TOPK];
    __shared__ ull   supmat[TOPK * 4];                     // 256-bit row per cand
    __shared__ ull   keepw[4];
    __shared__ unsigned int taken[(NB + 31) / 32];
    __shared__ float swv[4];  __shared__ int swi[4];  __shared__ int swp[4];
    __shared__ float bestv;   __shared__ int besti;   __shared__ int bestp;
    __shared__ int   Ksh;

    if (tid == 0) { scount = 0; Ksh = TOPK; }
    __syncthreads();

    // ---- phase 1: compact candidates (score > 0.05), float4 loads
    const float* row = scores_t + (size_t)c * NB;
    for (int i = tid; i < NB / 4; i += 256) {       // 8732 = 4*2183 exactly
        float4 v = ((const float4*)row)[i];
        int b0 = 4 * i;
        if (v.x > SCORE_MIN_F) { int p = atomicAdd(&scount, 1); if (p < SORT_CAP)
            skey[p] = ((ull)__float_as_uint(v.x) << 32) | (unsigned)(~(unsigned)(b0 + 0)); }
        if (v.y > SCORE_MIN_F) { int p = atomicAdd(&scount, 1); if (p < SORT_CAP)
            skey[p] = ((ull)__float_as_uint(v.y) << 32) | (unsigned)(~(unsigned)(b0 + 1)); }
        if (v.z > SCORE_MIN_F) { int p = atomicAdd(&scount, 1); if (p < SORT_CAP)
            skey[p] = ((ull)__float_as_uint(v.z) << 32) | (unsigned)(~(unsigned)(b0 + 2)); }
        if (v.w > SCORE_MIN_F) { int p = atomicAdd(&scount, 1); if (p < SORT_CAP)
            skey[p] = ((ull)__float_as_uint(v.w) << 32) | (unsigned)(~(unsigned)(b0 + 3)); }
    }
    __syncthreads();
    const int  M   = scount;
    const bool ovf = (M > SORT_CAP);
    int K;

    if (!ovf) {
        int N = 256;
        while (N < M) N <<= 1;
        for (int i = M + tid; i < N; i += 256) skey[i] = 0ull;
        bitonic_desc(skey, N, tid);                 // syncs internally
        K = (M < TOPK) ? M : TOPK;
        if (tid < K) {
            ull key = skey[tid];
            cval[tid] = __uint_as_float((unsigned)(key >> 32));
            int bi = (int)(~(unsigned)(key & 0xFFFFFFFFull));
            cbid[tid] = bi;
            cbox[tid] = ((const float4*)ltrb)[bi];
        }
        __syncthreads();
    } else {
        // ---- fallback: exact 200x argmax over global row (never in practice)
        for (int w = tid; w < (NB + 31) / 32; w += 256) taken[w] = 0u;
        __syncthreads();
        for (int k = 0; k < TOPK; k++) {
            float bv = -1e30f; int bi = 0x7fffffff; int bp = -1;
            for (int j = tid; j < NB; j += 256) {
                if (taken[j >> 5] & (1u << (j & 31))) continue;
                bmax3(bv, bi, bp, row[j], j, j);
            }
            block_best(bv, bi, bp, swv, swi, swp, &bestv, &besti, &bestp, tid);
            float gbv = bestv; int gbi = besti;
            if (gbv <= SCORE_MIN_F) { if (tid == 0) Ksh = k; __syncthreads(); break; }
            if (tid == 0) {
                cval[k] = gbv;
                cbid[k] = gbi;
                cbox[k] = ((const float4*)ltrb)[gbi];
                taken[gbi >> 5] |= (1u << (gbi & 31));
            }
            __syncthreads();
        }
        __syncthreads();
        K = Ksh;
    }

    // ---- phase 3: suppression bitmatrix — supmat[i*4+w] bit j = IOU>0.5, j<i
    for (int t = tid; t < K * 4; t += 256) {
        int i = t >> 2;
        int w = t & 3;
        ull bits = 0ull;
        int jlo = w * 64;
        int jhi = (jlo + 64 < i) ? (jlo + 64) : i;
        if (jlo < i) {
            float4 a = cbox[i];
            float areaA = (a.z - a.x) * (a.w - a.y);
            for (int j = jlo; j < jhi; j++) {
                float4 b = cbox[j];
                float lx = fmaxf(a.x, b.x), ly = fmaxf(a.y, b.y);
                float rx = fminf(a.z, b.z), ry = fminf(a.w, b.w);
                float ww = fmaxf(rx - lx, 0.0f), hh = fmaxf(ry - ly, 0.0f);
                float inter = ww * hh;
                float areaB = (b.z - b.x) * (b.w - b.y);
                float iou = inter / (areaA + areaB - inter);
                if (iou > NMS_IOU_F) bits |= (1ull << (j - jlo));
            }
        }
        supmat[t] = bits;
    }
    __syncthreads();

    // ---- phase 4: sequential greedy scan, software-pipelined prefetch
    if (tid == 0) {
        ull k0 = 0, k1 = 0, k2 = 0, k3 = 0;
        ull r0 = supmat[0], r1 = supmat[1], r2 = supmat[2], r3 = supmat[3];
        for (int i = 0; i < K; i++) {
            ull n0 = supmat[i * 4 + 4], n1 = supmat[i * 4 + 5];   // prefetch i+1
            ull n2 = supmat[i * 4 + 6], n3 = supmat[i * 4 + 7];   // (pad region ok)
            ull s = (r0 & k0) | (r1 & k1) | (r2 & k2) | (r3 & k3);
            if (s == 0ull) {
                if      (i < 64)  k0 |= 1ull << i;
                else if (i < 128) k1 |= 1ull << (i - 64);
                else if (i < 192) k2 |= 1ull << (i - 128);
                else              k3 |= 1ull << (i - 192);
            }
            r0 = n0; r1 = n1; r2 = n2; r3 = n3;
        }
        keepw[0] = k0; keepw[1] = k1; keepw[2] = k2; keepw[3] = k3;
    }
    __syncthreads();

    // ---- phase 5: outputs
    if (tid < TOPK) {
        int g = c * TOPK + tid;
        bool kept = (tid < K) && ((keepw[tid >> 6] >> (tid & 63)) & 1ull);
        cls_scores[g] = kept ? cval[tid] : 0.0f;
        cls_bidx[g]   = (tid < K) ? cbid[tid] : 0;
    }
}

// ---------------- kernel 4: global top-20 + final outputs -----------------
// Compact (>0.2) then bitonic sort; top-20 = first 20 sorted entries.
// Fallback (M > 8192, unreachable in practice): LDS argmax passes.
#define TK_CAP 8192

__global__ __launch_bounds__(256) void topk_kernel(const float* __restrict__ cls_scores,
                                                   const int* __restrict__ cls_bidx,
                                                   const float* __restrict__ ltrb,
                                                   float* __restrict__ out)
{
    const int tid = threadIdx.x;
    __shared__ __align__(16) ull buf[TK_CAP];     // 64 KB; fallback reuses as float[16000]
    __shared__ int   scount;
    __shared__ float swv[4];  __shared__ int swi[4];  __shared__ int swp[4];
    __shared__ float bestv;   __shared__ int besti;   __shared__ int bestp;
    __shared__ float selv[MAXOUT];
    __shared__ int   seli[MAXOUT];

    if (tid == 0) scount = 0;
    __syncthreads();

    for (int i = tid; i < NFLAT; i += 256) {      // 16000 = 62.5 iters..63
        float v = cls_scores[i];
        if (v > CONF_TH_F) {
            int p = atomicAdd(&scount, 1);
            if (p < TK_CAP)
                buf[p] = ((ull)__float_as_uint(v) << 32) | (unsigned)(~(unsigned)i);
        }
    }
    __syncthreads();
    const int  M   = scount;
    const bool ovf = (M > TK_CAP);

    if (!ovf) {
        int N = 32;
        while (N < M) N <<= 1;
        for (int i = M + tid; i < N; i += 256) buf[i] = 0ull;
        bitonic_desc(buf, N, tid);
        if (tid < MAXOUT) {
            if (tid < M) {
                ull key = buf[tid];
                selv[tid] = __uint_as_float((unsigned)(key >> 32));
                seli[tid] = (int)(~(unsigned)(key & 0xFFFFFFFFull));
            } else { selv[tid] = 0.0f; seli[tid] = 0; }
        }
        __syncthreads();
    } else {
        float* sv = (float*)buf;                  // 16000 floats = 62.5 KB
        for (int i = tid; i < NFLAT; i += 256) sv[i] = cls_scores[i];
        __syncthreads();
        for (int k = 0; k < MAXOUT; k++) {
            float bv = -1e30f; int bi = 0x7fffffff;
            for (int j = tid; j < NFLAT; j += 256) {
                float v = sv[j];
                if (v > bv || (v == bv && j < bi)) { bv = v; bi = j; }
            }
            block_best(bv, bi, bi, swv, swi, swp, &bestv, &besti, &bestp, tid);
            if (tid == 0) { selv[k] = bestv; seli[k] = besti; sv[besti] = -1e30f; }
            __syncthreads();
        }
    }

    if (tid < MAXOUT) {
        float v  = selv[tid];
        int   fi = seli[tid];
        bool  val = v > CONF_TH_F;
        int   cc  = fi / TOPK;
        int   orig = cls_bidx[fi];                  // 20 concurrent loads
        float4 bx = ((const float4*)ltrb)[orig];    // one dependent round
        float b0 = fminf(fmaxf(bx.x, 0.0f), 1.0f) * 4096.0f;
        float b1 = fminf(fmaxf(bx.y, 0.0f), 1.0f) * 4096.0f;
        float b2 = fminf(fmaxf(bx.z, 0.0f), 1.0f) * 4096.0f;
        float b3 = fminf(fmaxf(bx.w, 0.0f), 1.0f) * 4096.0f;
        out[B_OFF + 4 * tid + 0] = val ? b0 : 0.0f;
        out[B_OFF + 4 * tid + 1] = val ? b1 : 0.0f;
        out[B_OFF + 4 * tid + 2] = val ? b2 : 0.0f;
        out[B_OFF + 4 * tid + 3] = val ? b3 : 0.0f;
        out[L_OFF + tid] = val ? (float)COCO[cc] : 0.0f;
        out[S_OFF + tid] = val ? v : 0.0f;
        out[V_OFF + tid] = val ? 1.0f : 0.0f;
    }
}

// ---------------- launch ---------------------------------------------------
extern "C" void kernel_launch(void* const* d_in, const int* in_sizes, int n_in,
                              void* d_out, int out_size, void* d_ws, size_t ws_size,
                              hipStream_t stream)
{
    const float* image  = (const float*)d_in[0];
    const float* ploc   = (const float*)d_in[1];
    const float* plabel = (const float*)d_in[2];
    const float* dboxes = (const float*)d_in[3];
    float* out = (float*)d_out;

    float* ws        = (float*)d_ws;
    float* ltrb      = ws;                         // 8732*4 floats (16B aligned)
    float* scores_t  = ws + NB * 4;                // 80*8732 floats (16B aligned)
    float* cls_scores= scores_t + (size_t)NFG * NB;// 16000 floats
    int*   cls_bidx  = (int*)(cls_scores + NFLAT); // 16000 ints

    resize_kernel<<<3 * OHW, 256, 0, stream>>>(image, out);
    decode_kernel<<<(NB + 255) / 256, 256, 0, stream>>>(ploc, plabel, dboxes,
                                                        ltrb, scores_t);
    nms_kernel<<<NFG, 256, 0, stream>>>(scores_t, ltrb, cls_scores, cls_bidx);
    topk_kernel<<<1, 256, 0, stream>>>(cls_scores, cls_bidx, ltrb, out);
}

// Round 5
// 380.265 us; speedup vs baseline: 1.5196x; 1.5196x over previous
//
#include <hip/hip_runtime.h>
#include <math.h>

// ---------------- problem constants ----------------
#define NB      8732          // number of default boxes
#define NCLS    81            // classes incl. background
#define NFG     80            // foreground classes
#define TOPK    200           // per-class NMS candidates
#define MAXOUT  20            // final detections
#define NCAND   (NFG * MAXOUT) // 1600 global-topk candidates
#define SCORE_MIN_F 0.05f
#define NMS_IOU_F   0.5f
#define CONF_TH_F   0.2f
#define OHW     300
#define IHW     4096
#define X_ELEMS (3*OHW*OHW)   // 270000
#define B_OFF   270000
#define L_OFF   270080
#define S_OFF   270100
#define V_OFF   270120

typedef unsigned long long ull;

__device__ __constant__ int COCO[81] = {
  1,2,3,4,5,6,7,8,9,10,11,13,14,15,16,17,18,19,20,21,22,23,24,25,27,28,31,32,
  33,34,35,36,37,38,39,40,41,42,43,44,46,47,48,49,50,51,52,53,54,55,56,57,58,
  59,60,61,62,63,64,65,67,70,72,73,74,75,76,77,78,79,80,81,82,84,85,86,87,88,
  89,90,91};

// ---------------- kernel 1: normalize + bilinear resize (align_corners) ----
__global__ __launch_bounds__(256) void resize_kernel(const float* __restrict__ img,
                                                     float* __restrict__ out)
{
    const int b   = blockIdx.x;       // 0..899
    const int tid = threadIdx.x;
    const int ch  = b / OHW;
    const int oy  = b % OHW;

    const float r = (float)(4095.0 / 299.0);   // f32, matches jnp f32 promote
    float sy = (float)oy * r;
    int y0 = (int)floorf(sy);
    y0 = min(max(y0, 0), IHW - 2);
    float wy = sy - (float)y0;

    __shared__ __align__(16) float r0s[IHW];
    __shared__ __align__(16) float r1s[IHW];

    const float* p0 = img + (size_t)ch * IHW * IHW + (size_t)y0 * IHW;
    const float* p1 = p0 + IHW;
    #pragma unroll 4
    for (int i = tid; i < IHW / 4; i += 256) {
        float4 a = ((const float4*)p0)[i];
        float4 c = ((const float4*)p1)[i];
        a.x = (a.x * 255.0f - 128.0f) / 128.0f;
        a.y = (a.y * 255.0f - 128.0f) / 128.0f;
        a.z = (a.z * 255.0f - 128.0f) / 128.0f;
        a.w = (a.w * 255.0f - 128.0f) / 128.0f;
        c.x = (c.x * 255.0f - 128.0f) / 128.0f;
        c.y = (c.y * 255.0f - 128.0f) / 128.0f;
        c.z = (c.z * 255.0f - 128.0f) / 128.0f;
        c.w = (c.w * 255.0f - 128.0f) / 128.0f;
        ((float4*)r0s)[i] = a;
        ((float4*)r1s)[i] = c;
    }
    __syncthreads();

    float* orow = out + (size_t)ch * OHW * OHW + (size_t)oy * OHW;
    for (int ox = tid; ox < OHW; ox += 256) {
        float sx = (float)ox * r;
        int x0 = (int)floorf(sx);
        x0 = min(max(x0, 0), IHW - 2);
        float wx = sx - (float)x0;
        float left  = r0s[x0]     * (1.0f - wy) + r1s[x0]     * wy;
        float right = r0s[x0 + 1] * (1.0f - wy) + r1s[x0 + 1] * wy;
        orow[ox] = left * (1.0f - wx) + right * wx;
    }
}

// ---------------- kernel 2: decode boxes + softmax scores -----------------
__global__ __launch_bounds__(256) void decode_kernel(const float* __restrict__ ploc,
                                                     const float* __restrict__ plabel,
                                                     const float* __restrict__ dboxes,
                                                     float* __restrict__ ltrb,
                                                     float* __restrict__ scores_t)
{
    int i = blockIdx.x * 256 + threadIdx.x;
    if (i >= NB) return;

    float l0 = ploc[0 * NB + i];
    float l1 = ploc[1 * NB + i];
    float l2 = ploc[2 * NB + i];
    float l3 = ploc[3 * NB + i];
    float4 db = ((const float4*)dboxes)[i];   // x,y,w,h
    float x = (l0 * 0.1f) * db.z + db.x;
    float y = (l1 * 0.1f) * db.w + db.y;
    float w = expf(l2 * 0.2f) * db.z;
    float h = expf(l3 * 0.2f) * db.w;
    float4 bb;
    bb.x = x - 0.5f * w;
    bb.y = y - 0.5f * h;
    bb.z = x + 0.5f * w;
    bb.w = y + 0.5f * h;
    ((float4*)ltrb)[i] = bb;

    float mx = -1e30f;
    #pragma unroll 4
    for (int k = 0; k < NCLS; k++) mx = fmaxf(mx, plabel[k * NB + i]);
    float s = 0.0f;
    #pragma unroll 4
    for (int k = 0; k < NCLS; k++) s += expf(plabel[k * NB + i] - mx);
    #pragma unroll 4
    for (int c = 0; c < NFG; c++) {
        float e = expf(plabel[(c + 1) * NB + i] - mx);
        scores_t[c * NB + i] = e / s;
    }
}

// ---------------- helpers -------------------------------------------------
__device__ __forceinline__ void bmax3(float& av, int& ai, int& ap,
                                      float v, int i, int p)
{
    if (v > av || (v == av && i < ai)) { av = v; ai = i; ap = p; }
}

__device__ __forceinline__ void block_best(float bv, int bi, int bp,
                                           float* swv, int* swi, int* swp,
                                           volatile float* outv, volatile int* outi,
                                           volatile int* outp, int tid)
{
    for (int off = 32; off; off >>= 1) {
        float v2 = __shfl_down(bv, off, 64);
        int   i2 = __shfl_down(bi, off, 64);
        int   p2 = __shfl_down(bp, off, 64);
        bmax3(bv, bi, bp, v2, i2, p2);
    }
    int wid = tid >> 6;
    if ((tid & 63) == 0) { swv[wid] = bv; swi[wid] = bi; swp[wid] = bp; }
    __syncthreads();
    if (tid == 0) {
        float gv = swv[0]; int gi = swi[0]; int gp = swp[0];
        for (int w = 1; w < 4; w++) bmax3(gv, gi, gp, swv[w], swi[w], swp[w]);
        *outv = gv; *outi = gi; *outp = gp;
    }
    __syncthreads();
}

__device__ __forceinline__ ull shfl_down_u64(ull x, int off)
{
    unsigned lo = (unsigned)x, hi = (unsigned)(x >> 32);
    lo = __shfl_down(lo, off, 64);
    hi = __shfl_down(hi, off, 64);
    return ((ull)hi << 32) | lo;
}

// block-wide max of (u64 key, pos); tie (equal key) -> lower pos
__device__ __forceinline__ void block_best64(ull bk, int bp,
                                             ull* swk, int* swp,
                                             volatile ull* outk, volatile int* outp,
                                             int tid)
{
    for (int off = 32; off; off >>= 1) {
        ull k2 = shfl_down_u64(bk, off);
        int p2 = __shfl_down(bp, off, 64);
        if (k2 > bk || (k2 == bk && p2 < bp)) { bk = k2; bp = p2; }
    }
    int wid = tid >> 6;
    if ((tid & 63) == 0) { swk[wid] = bk; swp[wid] = bp; }
    __syncthreads();
    if (tid == 0) {
        ull gk = swk[0]; int gp = swp[0];
        for (int w = 1; w < 4; w++)
            if (swk[w] > gk || (swk[w] == gk && swp[w] < gp)) { gk = swk[w]; gp = swp[w]; }
        *outk = gk; *outp = gp;
    }
    __syncthreads();
}

// Pair-indexed bitonic sort, descending, u64 keys in LDS. 256 threads.
__device__ __forceinline__ void bitonic_desc(ull* key, int N, int tid)
{
    for (int k2 = 2; k2 <= N; k2 <<= 1) {
        for (int j = k2 >> 1; j > 0; j >>= 1) {
            __syncthreads();
            for (int p = tid; p < (N >> 1); p += 256) {
                int i = ((p & ~(j - 1)) << 1) | (p & (j - 1));
                int l = i | j;
                ull a = key[i], b = key[l];
                bool desc = ((i & k2) == 0);
                if (desc ? (a < b) : (a > b)) { key[i] = b; key[l] = a; }
            }
        }
    }
    __syncthreads();
}

// ---------------- kernel 3: per-class top-200 + NMS + per-class top-20 ----
#define SORT_CAP 4096

__global__ __launch_bounds__(256) void nms_kernel(const float* __restrict__ scores_t,
                                                  const float* __restrict__ ltrb,
                                                  ull* __restrict__ ckey,   // [NFG*20]
                                                  int* __restrict__ cb20)   // [NFG*20]
{
    const int c   = blockIdx.x;
    const int tid = threadIdx.x;

    __shared__ __align__(16) ull skey[SORT_CAP];           // 32 KB
    __shared__ int   scount;
    __shared__ float cval[TOPK];
    __shared__ int   cbid[TOPK];
    __shared__ float4 cbox[TOPK];
    __shared__ ull   supmat[TOPK * 4 + 4];                 // +4: prefetch pad
    __shared__ ull   keepw[4];
    __shared__ unsigned int taken[(NB + 31) / 32];
    __shared__ float swv[4];  __shared__ int swi[4];  __shared__ int swp[4];
    __shared__ float bestv;   __shared__ int besti;   __shared__ int bestp;
    __shared__ int   Ksh;

    if (tid == 0) { scount = 0; Ksh = TOPK; }
    __syncthreads();

    // ---- phase 1: compact candidates (score > 0.05), float4 loads
    const float* row = scores_t + (size_t)c * NB;
    for (int i = tid; i < NB / 4; i += 256) {       // 8732 = 4*2183 exactly
        float4 v = ((const float4*)row)[i];
        int b0 = 4 * i;
        if (v.x > SCORE_MIN_F) { int p = atomicAdd(&scount, 1); if (p < SORT_CAP)
            skey[p] = ((ull)__float_as_uint(v.x) << 32) | (unsigned)(~(unsigned)(b0 + 0)); }
        if (v.y > SCORE_MIN_F) { int p = atomicAdd(&scount, 1); if (p < SORT_CAP)
            skey[p] = ((ull)__float_as_uint(v.y) << 32) | (unsigned)(~(unsigned)(b0 + 1)); }
        if (v.z > SCORE_MIN_F) { int p = atomicAdd(&scount, 1); if (p < SORT_CAP)
            skey[p] = ((ull)__float_as_uint(v.z) << 32) | (unsigned)(~(unsigned)(b0 + 2)); }
        if (v.w > SCORE_MIN_F) { int p = atomicAdd(&scount, 1); if (p < SORT_CAP)
            skey[p] = ((ull)__float_as_uint(v.w) << 32) | (unsigned)(~(unsigned)(b0 + 3)); }
    }
    __syncthreads();
    const int  M   = scount;
    const bool ovf = (M > SORT_CAP);
    int K;

    if (!ovf) {
        int N = 256;
        while (N < M) N <<= 1;
        for (int i = M + tid; i < N; i += 256) skey[i] = 0ull;
        bitonic_desc(skey, N, tid);                 // syncs internally
        K = (M < TOPK) ? M : TOPK;
        if (tid < K) {
            ull key = skey[tid];
            cval[tid] = __uint_as_float((unsigned)(key >> 32));
            int bi = (int)(~(unsigned)(key & 0xFFFFFFFFull));
            cbid[tid] = bi;
            cbox[tid] = ((const float4*)ltrb)[bi];
        }
        __syncthreads();
    } else {
        // ---- fallback: exact 200x argmax over global row (never in practice)
        for (int w = tid; w < (NB + 31) / 32; w += 256) taken[w] = 0u;
        __syncthreads();
        for (int k = 0; k < TOPK; k++) {
            float bv = -1e30f; int bi = 0x7fffffff; int bp = -1;
            for (int j = tid; j < NB; j += 256) {
                if (taken[j >> 5] & (1u << (j & 31))) continue;
                bmax3(bv, bi, bp, row[j], j, j);
            }
            block_best(bv, bi, bp, swv, swi, swp, &bestv, &besti, &bestp, tid);
            float gbv = bestv; int gbi = besti;
            if (gbv <= SCORE_MIN_F) { if (tid == 0) Ksh = k; __syncthreads(); break; }
            if (tid == 0) {
                cval[k] = gbv;
                cbid[k] = gbi;
                cbox[k] = ((const float4*)ltrb)[gbi];
                taken[gbi >> 5] |= (1u << (gbi & 31));
            }
            __syncthreads();
        }
        __syncthreads();
        K = Ksh;
    }

    // ---- phase 3: suppression bitmatrix — supmat[i*4+w] bit j = IOU>0.5, j<i
    for (int t = tid; t < K * 4; t += 256) {
        int i = t >> 2;
        int w = t & 3;
        ull bits = 0ull;
        int jlo = w * 64;
        int jhi = (jlo + 64 < i) ? (jlo + 64) : i;
        if (jlo < i) {
            float4 a = cbox[i];
            float areaA = (a.z - a.x) * (a.w - a.y);
            for (int j = jlo; j < jhi; j++) {
                float4 b = cbox[j];
                float lx = fmaxf(a.x, b.x), ly = fmaxf(a.y, b.y);
                float rx = fminf(a.z, b.z), ry = fminf(a.w, b.w);
                float ww = fmaxf(rx - lx, 0.0f), hh = fmaxf(ry - ly, 0.0f);
                float inter = ww * hh;
                float areaB = (b.z - b.x) * (b.w - b.y);
                float iou = inter / (areaA + areaB - inter);
                if (iou > NMS_IOU_F) bits |= (1ull << (j - jlo));
            }
        }
        supmat[t] = bits;
    }
    __syncthreads();

    // ---- phase 4: sequential greedy scan, software-pipelined prefetch
    if (tid == 0) {
        ull k0 = 0, k1 = 0, k2 = 0, k3 = 0;
        ull r0 = supmat[0], r1 = supmat[1], r2 = supmat[2], r3 = supmat[3];
        for (int i = 0; i < K; i++) {
            ull n0 = supmat[i * 4 + 4], n1 = supmat[i * 4 + 5];   // prefetch i+1
            ull n2 = supmat[i * 4 + 6], n3 = supmat[i * 4 + 7];
            ull s = (r0 & k0) | (r1 & k1) | (r2 & k2) | (r3 & k3);
            if (s == 0ull) {
                if      (i < 64)  k0 |= 1ull << i;
                else if (i < 128) k1 |= 1ull << (i - 64);
                else if (i < 192) k2 |= 1ull << (i - 128);
                else              k3 |= 1ull << (i - 192);
            }
            r0 = n0; r1 = n1; r2 = n2; r3 = n3;
        }
        keepw[0] = k0; keepw[1] = k1; keepw[2] = k2; keepw[3] = k3;
    }
    __syncthreads();

    // ---- phase 5: emit per-class top-20 kept entries (sorted, exact order).
    // Any kept entry past rank 20 can never enter the global top-20: 20
    // same-class entries with >= value and lower flat index precede it.
    if (tid < MAXOUT) { ckey[c * MAXOUT + tid] = 0ull; cb20[c * MAXOUT + tid] = 0; }
    __syncthreads();
    if (tid < K) {
        int wid = tid >> 6;
        ull w = keepw[wid];
        if ((w >> (tid & 63)) & 1ull) {
            int rank = __popcll(w & ((1ull << (tid & 63)) - 1ull));
            for (int q = 0; q < wid; q++) rank += __popcll(keepw[q]);
            if (rank < MAXOUT) {
                int flat = c * TOPK + tid;   // exact flat index in ref's 16000
                ckey[c * MAXOUT + rank] =
                    ((ull)__float_as_uint(cval[tid]) << 32) | (unsigned)(~(unsigned)flat);
                cb20[c * MAXOUT + rank] = cbid[tid];
            }
        }
    }
}

// ---------------- kernel 4: global top-20 over 1600 candidates ------------
__global__ __launch_bounds__(256) void topk_kernel(const ull* __restrict__ ckey,
                                                   const int* __restrict__ cb20,
                                                   const float* __restrict__ ltrb,
                                                   float* __restrict__ out)
{
    const int tid = threadIdx.x;
    __shared__ ull sk[NCAND];                     // 12.8 KB
    __shared__ ull swk[4];  __shared__ int swp[4];
    __shared__ ull bestk;   __shared__ int bestp;
    __shared__ ull selk[MAXOUT];
    __shared__ int selp[MAXOUT];

    for (int i = tid; i < NCAND; i += 256) sk[i] = ckey[i];
    __syncthreads();

    for (int k = 0; k < MAXOUT; k++) {
        ull bk = 0ull; int bp = 0x7fffffff;
        #pragma unroll
        for (int j = tid; j < NCAND; j += 256) {
            ull v = sk[j];
            if (v > bk || (v == bk && j < bp)) { bk = v; bp = j; }
        }
        block_best64(bk, bp, swk, swp, &bestk, &bestp, tid);
        if (tid == 0) { selk[k] = bestk; selp[k] = bestp; sk[bestp] = 0ull; }
        __syncthreads();
    }

    if (tid < MAXOUT) {
        ull key = selk[tid];
        float v  = __uint_as_float((unsigned)(key >> 32));
        int   fi = (int)(~(unsigned)(key & 0xFFFFFFFFull));
        bool  val = v > CONF_TH_F;
        int   cc  = (fi >= 0) ? (fi / TOPK) : 0;
        int   orig = cb20[selp[tid]];
        float4 bx = ((const float4*)ltrb)[orig];
        float b0 = fminf(fmaxf(bx.x, 0.0f), 1.0f) * 4096.0f;
        float b1 = fminf(fmaxf(bx.y, 0.0f), 1.0f) * 4096.0f;
        float b2 = fminf(fmaxf(bx.z, 0.0f), 1.0f) * 4096.0f;
        float b3 = fminf(fmaxf(bx.w, 0.0f), 1.0f) * 4096.0f;
        out[B_OFF + 4 * tid + 0] = val ? b0 : 0.0f;
        out[B_OFF + 4 * tid + 1] = val ? b1 : 0.0f;
        out[B_OFF + 4 * tid + 2] = val ? b2 : 0.0f;
        out[B_OFF + 4 * tid + 3] = val ? b3 : 0.0f;
        out[L_OFF + tid] = val ? (float)COCO[cc] : 0.0f;
        out[S_OFF + tid] = val ? v : 0.0f;
        out[V_OFF + tid] = val ? 1.0f : 0.0f;
    }
}

// ---------------- launch ---------------------------------------------------
extern "C" void kernel_launch(void* const* d_in, const int* in_sizes, int n_in,
                              void* d_out, int out_size, void* d_ws, size_t ws_size,
                              hipStream_t stream)
{
    const float* image  = (const float*)d_in[0];
    const float* ploc   = (const float*)d_in[1];
    const float* plabel = (const float*)d_in[2];
    const float* dboxes = (const float*)d_in[3];
    float* out = (float*)d_out;

    float* ws        = (float*)d_ws;
    float* ltrb      = ws;                          // 8732*4 floats (16B aligned)
    float* scores_t  = ws + NB * 4;                 // 80*8732 floats
    ull*   ckey      = (ull*)(scores_t + (size_t)NFG * NB);  // 1600 u64 (8B aligned)
    int*   cb20      = (int*)(ckey + NCAND);        // 1600 ints

    resize_kernel<<<3 * OHW, 256, 0, stream>>>(image, out);
    decode_kernel<<<(NB + 255) / 256, 256, 0, stream>>>(ploc, plabel, dboxes,
                                                        ltrb, scores_t);
    nms_kernel<<<NFG, 256, 0, stream>>>(scores_t, ltrb, ckey, cb20);
    topk_kernel<<<1, 256, 0, stream>>>(ckey, cb20, ltrb, out);
}

// Round 6
// 375.582 us; speedup vs baseline: 1.5385x; 1.0125x over previous
//
#include <hip/hip_runtime.h>
#include <math.h>

// ---------------- problem constants ----------------
#define NB      8732          // number of default boxes
#define NCLS    81            // classes incl. background
#define NFG     80            // foreground classes
#define TOPK    200           // per-class NMS candidates
#define MAXOUT  20            // final detections
#define NCAND   (NFG * MAXOUT) // 1600 global-topk candidates
#define SCORE_MIN_F 0.05f
#define NMS_IOU_F   0.5f
#define CONF_TH_F   0.2f
#define OHW     300
#define IHW     4096
#define X_ELEMS (3*OHW*OHW)   // 270000
#define B_OFF   270000
#define L_OFF   270080
#define S_OFF   270100
#define V_OFF   270120

typedef unsigned long long ull;

__device__ __constant__ int COCO[81] = {
  1,2,3,4,5,6,7,8,9,10,11,13,14,15,16,17,18,19,20,21,22,23,24,25,27,28,31,32,
  33,34,35,36,37,38,39,40,41,42,43,44,46,47,48,49,50,51,52,53,54,55,56,57,58,
  59,60,61,62,63,64,65,67,70,72,73,74,75,76,77,78,79,80,81,82,84,85,86,87,88,
  89,90,91};

// ---------------- kernel 1: normalize + bilinear resize (align_corners) ----
__global__ __launch_bounds__(256) void resize_kernel(const float* __restrict__ img,
                                                     float* __restrict__ out)
{
    const int b   = blockIdx.x;       // 0..899
    const int tid = threadIdx.x;
    const int ch  = b / OHW;
    const int oy  = b % OHW;

    const float r = (float)(4095.0 / 299.0);   // f32, matches jnp f32 promote
    float sy = (float)oy * r;
    int y0 = (int)floorf(sy);
    y0 = min(max(y0, 0), IHW - 2);
    float wy = sy - (float)y0;

    __shared__ __align__(16) float r0s[IHW];
    __shared__ __align__(16) float r1s[IHW];

    const float* p0 = img + (size_t)ch * IHW * IHW + (size_t)y0 * IHW;
    const float* p1 = p0 + IHW;
    #pragma unroll 4
    for (int i = tid; i < IHW / 4; i += 256) {
        float4 a = ((const float4*)p0)[i];
        float4 c = ((const float4*)p1)[i];
        a.x = (a.x * 255.0f - 128.0f) / 128.0f;
        a.y = (a.y * 255.0f - 128.0f) / 128.0f;
        a.z = (a.z * 255.0f - 128.0f) / 128.0f;
        a.w = (a.w * 255.0f - 128.0f) / 128.0f;
        c.x = (c.x * 255.0f - 128.0f) / 128.0f;
        c.y = (c.y * 255.0f - 128.0f) / 128.0f;
        c.z = (c.z * 255.0f - 128.0f) / 128.0f;
        c.w = (c.w * 255.0f - 128.0f) / 128.0f;
        ((float4*)r0s)[i] = a;
        ((float4*)r1s)[i] = c;
    }
    __syncthreads();

    float* orow = out + (size_t)ch * OHW * OHW + (size_t)oy * OHW;
    for (int ox = tid; ox < OHW; ox += 256) {
        float sx = (float)ox * r;
        int x0 = (int)floorf(sx);
        x0 = min(max(x0, 0), IHW - 2);
        float wx = sx - (float)x0;
        float left  = r0s[x0]     * (1.0f - wy) + r1s[x0]     * wy;
        float right = r0s[x0 + 1] * (1.0f - wy) + r1s[x0 + 1] * wy;
        orow[ox] = left * (1.0f - wx) + right * wx;
    }
}

// ---------------- kernel 2: decode boxes + softmax scores -----------------
__global__ __launch_bounds__(256) void decode_kernel(const float* __restrict__ ploc,
                                                     const float* __restrict__ plabel,
                                                     const float* __restrict__ dboxes,
                                                     float* __restrict__ ltrb,
                                                     float* __restrict__ scores_t)
{
    int i = blockIdx.x * 256 + threadIdx.x;
    if (i >= NB) return;

    float l0 = ploc[0 * NB + i];
    float l1 = ploc[1 * NB + i];
    float l2 = ploc[2 * NB + i];
    float l3 = ploc[3 * NB + i];
    float4 db = ((const float4*)dboxes)[i];   // x,y,w,h
    float x = (l0 * 0.1f) * db.z + db.x;
    float y = (l1 * 0.1f) * db.w + db.y;
    float w = expf(l2 * 0.2f) * db.z;
    float h = expf(l3 * 0.2f) * db.w;
    float4 bb;
    bb.x = x - 0.5f * w;
    bb.y = y - 0.5f * h;
    bb.z = x + 0.5f * w;
    bb.w = y + 0.5f * h;
    ((float4*)ltrb)[i] = bb;

    float mx = -1e30f;
    #pragma unroll 4
    for (int k = 0; k < NCLS; k++) mx = fmaxf(mx, plabel[k * NB + i]);
    float s = 0.0f;
    #pragma unroll 4
    for (int k = 0; k < NCLS; k++) s += expf(plabel[k * NB + i] - mx);
    #pragma unroll 4
    for (int c = 0; c < NFG; c++) {
        float e = expf(plabel[(c + 1) * NB + i] - mx);
        scores_t[c * NB + i] = e / s;
    }
}

// ---------------- helpers -------------------------------------------------
__device__ __forceinline__ void bmax3(float& av, int& ai, int& ap,
                                      float v, int i, int p)
{
    if (v > av || (v == av && i < ai)) { av = v; ai = i; ap = p; }
}

__device__ __forceinline__ void block_best(float bv, int bi, int bp,
                                           float* swv, int* swi, int* swp,
                                           volatile float* outv, volatile int* outi,
                                           volatile int* outp, int tid)
{
    for (int off = 32; off; off >>= 1) {
        float v2 = __shfl_down(bv, off, 64);
        int   i2 = __shfl_down(bi, off, 64);
        int   p2 = __shfl_down(bp, off, 64);
        bmax3(bv, bi, bp, v2, i2, p2);
    }
    int wid = tid >> 6;
    if ((tid & 63) == 0) { swv[wid] = bv; swi[wid] = bi; swp[wid] = bp; }
    __syncthreads();
    if (tid == 0) {
        float gv = swv[0]; int gi = swi[0]; int gp = swp[0];
        for (int w = 1; w < 4; w++) bmax3(gv, gi, gp, swv[w], swi[w], swp[w]);
        *outv = gv; *outi = gi; *outp = gp;
    }
    __syncthreads();
}

__device__ __forceinline__ ull shfl_down_u64(ull x, int off)
{
    unsigned lo = (unsigned)x, hi = (unsigned)(x >> 32);
    lo = __shfl_down(lo, off, 64);
    hi = __shfl_down(hi, off, 64);
    return ((ull)hi << 32) | lo;
}

// block-wide max of (u64 key, pos); tie (equal key) -> lower pos
__device__ __forceinline__ void block_best64(ull bk, int bp,
                                             ull* swk, int* swp,
                                             volatile ull* outk, volatile int* outp,
                                             int tid)
{
    for (int off = 32; off; off >>= 1) {
        ull k2 = shfl_down_u64(bk, off);
        int p2 = __shfl_down(bp, off, 64);
        if (k2 > bk || (k2 == bk && p2 < bp)) { bk = k2; bp = p2; }
    }
    int wid = tid >> 6;
    if ((tid & 63) == 0) { swk[wid] = bk; swp[wid] = bp; }
    __syncthreads();
    if (tid == 0) {
        ull gk = swk[0]; int gp = swp[0];
        for (int w = 1; w < 4; w++)
            if (swk[w] > gk || (swk[w] == gk && swp[w] < gp)) { gk = swk[w]; gp = swp[w]; }
        *outk = gk; *outp = gp;
    }
    __syncthreads();
}

// Pair-indexed bitonic sort, descending, u64 keys in LDS. 256 threads.
__device__ __forceinline__ void bitonic_desc(ull* key, int N, int tid)
{
    for (int k2 = 2; k2 <= N; k2 <<= 1) {
        for (int j = k2 >> 1; j > 0; j >>= 1) {
            __syncthreads();
            for (int p = tid; p < (N >> 1); p += 256) {
                int i = ((p & ~(j - 1)) << 1) | (p & (j - 1));
                int l = i | j;
                ull a = key[i], b = key[l];
                bool desc = ((i & k2) == 0);
                if (desc ? (a < b) : (a > b)) { key[i] = b; key[l] = a; }
            }
        }
    }
    __syncthreads();
}

// ---------------- kernel 3: per-class radix-select top-200 + NMS ----------
#define SORT_CAP 4096
#define NBINS    1024
#define BBASE    0x3D4C      // __float_as_uint(0.05f) >> 16

__global__ __launch_bounds__(256) void nms_kernel(const float* __restrict__ scores_t,
                                                  const float* __restrict__ ltrb,
                                                  ull* __restrict__ ckey,   // [NFG*20]
                                                  int* __restrict__ cb20)   // [NFG*20]
{
    const int c    = blockIdx.x;
    const int tid  = threadIdx.x;
    const int lane = tid & 63;
    const ull ltm  = (1ull << lane) - 1ull;

    __shared__ __align__(16) ull skey[SORT_CAP];           // 32 KB
    __shared__ int   hist[NBINS];                          // 4 KB
    __shared__ int   ssum[256];                            // 1 KB
    __shared__ int   scount;
    __shared__ int   bstar;
    __shared__ int   Csh;
    __shared__ float cval[TOPK];
    __shared__ int   cbid[TOPK];
    __shared__ float4 cbox[TOPK];
    __shared__ ull   supmat[TOPK * 4 + 4];                 // +4: prefetch pad
    __shared__ ull   keepw[4];
    __shared__ unsigned int taken[(NB + 31) / 32];
    __shared__ float swv[4];  __shared__ int swi[4];  __shared__ int swp[4];
    __shared__ float bestv;   __shared__ int besti;   __shared__ int bestp;
    __shared__ int   Ksh;

    if (tid == 0) { scount = 0; Ksh = TOPK; }
    for (int i = tid; i < NBINS; i += 256) hist[i] = 0;
    __syncthreads();

    // ---- phase A: histogram of scores > 0.05 over monotone float-bit bins
    // bucket(v) = (bits(v)>>16) - 0x3D4C; exact-monotone for v in (0.05, 1].
    const float* row = scores_t + (size_t)c * NB;
    for (int i = tid; i < NB / 4; i += 256) {       // 8732 = 4*2183 exactly
        float4 v = ((const float4*)row)[i];
        if (v.x > SCORE_MIN_F)
            atomicAdd(&hist[min((int)(__float_as_uint(v.x) >> 16) - BBASE, NBINS - 1)], 1);
        if (v.y > SCORE_MIN_F)
            atomicAdd(&hist[min((int)(__float_as_uint(v.y) >> 16) - BBASE, NBINS - 1)], 1);
        if (v.z > SCORE_MIN_F)
            atomicAdd(&hist[min((int)(__float_as_uint(v.z) >> 16) - BBASE, NBINS - 1)], 1);
        if (v.w > SCORE_MIN_F)
            atomicAdd(&hist[min((int)(__float_as_uint(v.w) >> 16) - BBASE, NBINS - 1)], 1);
    }
    __syncthreads();

    // ---- phase B: suffix scan to find cutoff bucket bstar and count C.
    // bstar = largest b with suffix(b) >= 200 (else 0); C = suffix(bstar).
    int c0 = hist[4 * tid], c1 = hist[4 * tid + 1];
    int c2 = hist[4 * tid + 2], c3 = hist[4 * tid + 3];
    ssum[tid] = c0 + c1 + c2 + c3;
    __syncthreads();
    for (int off = 1; off < 256; off <<= 1) {
        int add = (tid + off < 256) ? ssum[tid + off] : 0;
        __syncthreads();
        ssum[tid] += add;
        __syncthreads();
    }
    if (tid == 0) { bstar = 0; Csh = ssum[0]; }   // default: take all (M<200)
    __syncthreads();
    {
        int s = ssum[tid];                        // suffix at bin 4*tid
        int cc[4] = {c0, c1, c2, c3};
        #pragma unroll
        for (int k = 0; k < 4; k++) {
            if (s >= TOPK && s - cc[k] < TOPK) { bstar = 4 * tid + k; Csh = s; }
            s -= cc[k];
        }
    }
    __syncthreads();
    const int bs = bstar;
    const int C  = Csh;
    int K;

    if (C <= SORT_CAP) {
        // ---- phase C: wave-aggregated compaction of buckets >= bstar
        for (int i = tid; i < NB / 4; i += 256) {
            float4 v = ((const float4*)row)[i];
            int b0 = 4 * i;
            #pragma unroll
            for (int kq = 0; kq < 4; kq++) {
                float vv = (kq == 0) ? v.x : (kq == 1) ? v.y : (kq == 2) ? v.z : v.w;
                unsigned u = __float_as_uint(vv);
                bool pred = (vv > SCORE_MIN_F) &&
                            (min((int)(u >> 16) - BBASE, NBINS - 1) >= bs);
                ull m = __ballot(pred);
                if (m) {
                    int lead = __ffsll((long long)m) - 1;
                    int base = 0;
                    if (lane == lead) base = atomicAdd(&scount, __popcll(m));
                    base = __shfl(base, lead, 64);
                    if (pred) {
                        int p = base + __popcll(m & ltm);
                        skey[p] = ((ull)u << 32) | (unsigned)(~(unsigned)(b0 + kq));
                    }
                }
            }
        }
        __syncthreads();
        // ---- small bitonic sort (C ~ 200-300 expected)
        int N = 64;
        while (N < C) N <<= 1;
        for (int i = C + tid; i < N; i += 256) skey[i] = 0ull;
        bitonic_desc(skey, N, tid);               // syncs internally
        K = (C < TOPK) ? C : TOPK;
        if (tid < K) {
            ull key = skey[tid];
            cval[tid] = __uint_as_float((unsigned)(key >> 32));
            int bi = (int)(~(unsigned)(key & 0xFFFFFFFFull));
            cbid[tid] = bi;
            cbox[tid] = ((const float4*)ltrb)[bi];
        }
        __syncthreads();
    } else {
        // ---- fallback: exact 200x argmax over global row (unreachable-ish)
        for (int w = tid; w < (NB + 31) / 32; w += 256) taken[w] = 0u;
        __syncthreads();
        for (int k = 0; k < TOPK; k++) {
            float bv = -1e30f; int bi = 0x7fffffff; int bp = -1;
            for (int j = tid; j < NB; j += 256) {
                if (taken[j >> 5] & (1u << (j & 31))) continue;
                bmax3(bv, bi, bp, row[j], j, j);
            }
            block_best(bv, bi, bp, swv, swi, swp, &bestv, &besti, &bestp, tid);
            float gbv = bestv; int gbi = besti;
            if (gbv <= SCORE_MIN_F) { if (tid == 0) Ksh = k; __syncthreads(); break; }
            if (tid == 0) {
                cval[k] = gbv;
                cbid[k] = gbi;
                cbox[k] = ((const float4*)ltrb)[gbi];
                taken[gbi >> 5] |= (1u << (gbi & 31));
            }
            __syncthreads();
        }
        __syncthreads();
        K = Ksh;
    }

    // ---- phase 3: suppression bitmatrix — supmat[i*4+w] bit j = IOU>0.5, j<i
    for (int t = tid; t < K * 4; t += 256) {
        int i = t >> 2;
        int w = t & 3;
        ull bits = 0ull;
        int jlo = w * 64;
        int jhi = (jlo + 64 < i) ? (jlo + 64) : i;
        if (jlo < i) {
            float4 a = cbox[i];
            float areaA = (a.z - a.x) * (a.w - a.y);
            for (int j = jlo; j < jhi; j++) {
                float4 b = cbox[j];
                float lx = fmaxf(a.x, b.x), ly = fmaxf(a.y, b.y);
                float rx = fminf(a.z, b.z), ry = fminf(a.w, b.w);
                float ww = fmaxf(rx - lx, 0.0f), hh = fmaxf(ry - ly, 0.0f);
                float inter = ww * hh;
                float areaB = (b.z - b.x) * (b.w - b.y);
                float iou = inter / (areaA + areaB - inter);
                if (iou > NMS_IOU_F) bits |= (1ull << (j - jlo));
            }
        }
        supmat[t] = bits;
    }
    __syncthreads();

    // ---- phase 4: sequential greedy scan, software-pipelined prefetch
    if (tid == 0) {
        ull k0 = 0, k1 = 0, k2 = 0, k3 = 0;
        ull r0 = supmat[0], r1 = supmat[1], r2 = supmat[2], r3 = supmat[3];
        for (int i = 0; i < K; i++) {
            ull n0 = supmat[i * 4 + 4], n1 = supmat[i * 4 + 5];   // prefetch i+1
            ull n2 = supmat[i * 4 + 6], n3 = supmat[i * 4 + 7];
            ull s = (r0 & k0) | (r1 & k1) | (r2 & k2) | (r3 & k3);
            if (s == 0ull) {
                if      (i < 64)  k0 |= 1ull << i;
                else if (i < 128) k1 |= 1ull << (i - 64);
                else if (i < 192) k2 |= 1ull << (i - 128);
                else              k3 |= 1ull << (i - 192);
            }
            r0 = n0; r1 = n1; r2 = n2; r3 = n3;
        }
        keepw[0] = k0; keepw[1] = k1; keepw[2] = k2; keepw[3] = k3;
    }
    __syncthreads();

    // ---- phase 5: emit per-class top-20 kept entries (sorted, exact order).
    if (tid < MAXOUT) { ckey[c * MAXOUT + tid] = 0ull; cb20[c * MAXOUT + tid] = 0; }
    __syncthreads();
    if (tid < K) {
        int wid = tid >> 6;
        ull w = keepw[wid];
        if ((w >> (tid & 63)) & 1ull) {
            int rank = __popcll(w & ((1ull << (tid & 63)) - 1ull));
            for (int q = 0; q < wid; q++) rank += __popcll(keepw[q]);
            if (rank < MAXOUT) {
                int flat = c * TOPK + tid;   // exact flat index in ref's 16000
                ckey[c * MAXOUT + rank] =
                    ((ull)__float_as_uint(cval[tid]) << 32) | (unsigned)(~(unsigned)flat);
                cb20[c * MAXOUT + rank] = cbid[tid];
            }
        }
    }
}

// ---------------- kernel 4: global top-20 over 1600 candidates ------------
__global__ __launch_bounds__(256) void topk_kernel(const ull* __restrict__ ckey,
                                                   const int* __restrict__ cb20,
                                                   const float* __restrict__ ltrb,
                                                   float* __restrict__ out)
{
    const int tid = threadIdx.x;
    __shared__ ull sk[NCAND];                     // 12.8 KB
    __shared__ ull swk[4];  __shared__ int swp[4];
    __shared__ ull bestk;   __shared__ int bestp;
    __shared__ ull selk[MAXOUT];
    __shared__ int selp[MAXOUT];

    for (int i = tid; i < NCAND; i += 256) sk[i] = ckey[i];
    __syncthreads();

    for (int k = 0; k < MAXOUT; k++) {
        ull bk = 0ull; int bp = 0x7fffffff;
        #pragma unroll
        for (int j = tid; j < NCAND; j += 256) {
            ull v = sk[j];
            if (v > bk || (v == bk && j < bp)) { bk = v; bp = j; }
        }
        block_best64(bk, bp, swk, swp, &bestk, &bestp, tid);
        if (tid == 0) { selk[k] = bestk; selp[k] = bestp; sk[bestp] = 0ull; }
        __syncthreads();
    }

    if (tid < MAXOUT) {
        ull key = selk[tid];
        float v  = __uint_as_float((unsigned)(key >> 32));
        int   fi = (int)(~(unsigned)(key & 0xFFFFFFFFull));
        bool  val = v > CONF_TH_F;
        int   cc  = (fi >= 0) ? (fi / TOPK) : 0;
        int   orig = cb20[selp[tid]];
        float4 bx = ((const float4*)ltrb)[orig];
        float b0 = fminf(fmaxf(bx.x, 0.0f), 1.0f) * 4096.0f;
        float b1 = fminf(fmaxf(bx.y, 0.0f), 1.0f) * 4096.0f;
        float b2 = fminf(fmaxf(bx.z, 0.0f), 1.0f) * 4096.0f;
        float b3 = fminf(fmaxf(bx.w, 0.0f), 1.0f) * 4096.0f;
        out[B_OFF + 4 * tid + 0] = val ? b0 : 0.0f;
        out[B_OFF + 4 * tid + 1] = val ? b1 : 0.0f;
        out[B_OFF + 4 * tid + 2] = val ? b2 : 0.0f;
        out[B_OFF + 4 * tid + 3] = val ? b3 : 0.0f;
        out[L_OFF + tid] = val ? (float)COCO[cc] : 0.0f;
        out[S_OFF + tid] = val ? v : 0.0f;
        out[V_OFF + tid] = val ? 1.0f : 0.0f;
    }
}

// ---------------- launch ---------------------------------------------------
extern "C" void kernel_launch(void* const* d_in, const int* in_sizes, int n_in,
                              void* d_out, int out_size, void* d_ws, size_t ws_size,
                              hipStream_t stream)
{
    const float* image  = (const float*)d_in[0];
    const float* ploc   = (const float*)d_in[1];
    const float* plabel = (const float*)d_in[2];
    const float* dboxes = (const float*)d_in[3];
    float* out = (float*)d_out;

    float* ws        = (float*)d_ws;
    float* ltrb      = ws;                          // 8732*4 floats (16B aligned)
    float* scores_t  = ws + NB * 4;                 // 80*8732 floats
    ull*   ckey      = (ull*)(scores_t + (size_t)NFG * NB);  // 1600 u64 (8B aligned)
    int*   cb20      = (int*)(ckey + NCAND);        // 1600 ints

    resize_kernel<<<3 * OHW, 256, 0, stream>>>(image, out);
    decode_kernel<<<(NB + 255) / 256, 256, 0, stream>>>(ploc, plabel, dboxes,
                                                        ltrb, scores_t);
    nms_kernel<<<NFG, 256, 0, stream>>>(scores_t, ltrb, ckey, cb20);
    topk_kernel<<<1, 256, 0, stream>>>(ckey, cb20, ltrb, out);
}